// Round 4
// baseline (826.597 us; speedup 1.0000x reference)
//
#include <hip/hip_runtime.h>
#include <cstddef>

// Problem constants
#define Bn 8
#define Sn 1024
#define Hn 12
#define Dn 768
#define En 64          // head dim
#define Mn (Bn * Sn)   // 8192 rows

typedef unsigned short ushort_t;
typedef __attribute__((ext_vector_type(4))) float f32x4;
typedef __attribute__((ext_vector_type(16))) float f32x16;
typedef __bf16 bf16x8 __attribute__((ext_vector_type(8)));

#define MFMA(a, b, c)   __builtin_amdgcn_mfma_f32_16x16x32_bf16(a, b, c, 0, 0, 0)
#define MFMA32(a, b, c) __builtin_amdgcn_mfma_f32_32x32x16_bf16(a, b, c, 0, 0, 0)

// RNE f32 -> bf16 (inputs finite; NaN not handled)
__device__ __forceinline__ ushort_t bf_hi(float f) {
    unsigned int u = __float_as_uint(f);
    return (ushort_t)((u + 0x7FFF + ((u >> 16) & 1)) >> 16);
}
__device__ __forceinline__ float bf_f(ushort_t s) {
    return __uint_as_float(((unsigned int)s) << 16);
}

// global -> LDS direct copy, 16B per lane
#define GLL16(gp, lp)                                                        \
    __builtin_amdgcn_global_load_lds(                                        \
        (__attribute__((address_space(1))) void*)(gp),                       \
        (__attribute__((address_space(3))) void*)(lp), 16, 0, 0)

// ---------------------------------------------------------------------------
// Pre-pass A: split x [8192][768] f32 into hi/lo bf16 (same layout).
// ---------------------------------------------------------------------------
__global__ __launch_bounds__(256) void split_x_kernel(
    const float4* __restrict__ x4,
    ushort_t* __restrict__ xh, ushort_t* __restrict__ xl)
{
    int idx = blockIdx.x * 256 + threadIdx.x;   // 0 .. 1572863
    float4 f = x4[idx];
    ushort_t h0 = bf_hi(f.x), h1 = bf_hi(f.y), h2 = bf_hi(f.z), h3 = bf_hi(f.w);
    ushort_t l0 = bf_hi(f.x - bf_f(h0));
    ushort_t l1 = bf_hi(f.y - bf_f(h1));
    ushort_t l2 = bf_hi(f.z - bf_f(h2));
    ushort_t l3 = bf_hi(f.w - bf_f(h3));
    *(ushort4*)&xh[(size_t)idx * 4] = make_ushort4(h0, h1, h2, h3);
    *(ushort4*)&xl[(size_t)idx * 4] = make_ushort4(l0, l1, l2, l3);
}

// ---------------------------------------------------------------------------
// Pre-pass B: split + transpose W[h][d][e] -> Wt[w][h][e][d] hi/lo bf16.
// ---------------------------------------------------------------------------
__global__ __launch_bounds__(256) void split_w_kernel(
    const float* __restrict__ Wq, const float* __restrict__ Wk,
    const float* __restrict__ Wv,
    ushort_t* __restrict__ wth, ushort_t* __restrict__ wtl)
{
    const int dt = blockIdx.x;   // 0..11 (64-wide d tile)
    const int h  = blockIdx.y;   // 0..11
    const int w  = blockIdx.z;   // 0..2
    const float* Wp = (w == 0) ? Wq : (w == 1) ? Wk : Wv;

    __shared__ float Ws[64][65];
    const int tid = threadIdx.x;

    #pragma unroll
    for (int t = 0; t < 16; ++t) {
        int idx = tid + t * 256;          // 0..4095
        int d = idx >> 6, e = idx & 63;
        Ws[d][e] = Wp[((size_t)h * Dn + dt * 64 + d) * En + e];
    }
    __syncthreads();

    ushort_t* oh = wth + ((size_t)w * Hn + h) * En * Dn;
    ushort_t* ol = wtl + ((size_t)w * Hn + h) * En * Dn;
    #pragma unroll
    for (int t = 0; t < 16; ++t) {
        int idx = tid + t * 256;
        int e = idx >> 6, dd = idx & 63;
        float f = Ws[dd][e];
        ushort_t hi = bf_hi(f);
        oh[(size_t)e * Dn + dt * 64 + dd] = hi;
        ol[(size_t)e * Dn + dt * 64 + dd] = bf_hi(f - bf_f(hi));
    }
}

// ---------------------------------------------------------------------------
// Kernel 1: QKV projection via bf16x3 MFMA.  Outputs bf16 hi/lo directly:
//   Q,K: [bh][s][e];  V transposed: [bh][e][s]  (PV A-operand layout).
// Tile 128(m) x 64(e), BK=64.  LDS XOR-swizzled (^((row&7)<<3) ushort idx).
// ---------------------------------------------------------------------------
__global__ __launch_bounds__(256) void qkv_mfma_kernel(
    const ushort_t* __restrict__ xh, const ushort_t* __restrict__ xl,
    const ushort_t* __restrict__ wth, const ushort_t* __restrict__ wtl,
    const float* __restrict__ bq, const float* __restrict__ bk,
    const float* __restrict__ bv,
    ushort_t* __restrict__ Qh, ushort_t* __restrict__ Ql,
    ushort_t* __restrict__ Kh, ushort_t* __restrict__ Kl,
    ushort_t* __restrict__ Vth, ushort_t* __restrict__ Vtl)
{
    const int mt = blockIdx.x;   // 0..63
    const int h  = blockIdx.y;   // 0..11
    const int w  = blockIdx.z;   // 0..2
    const float* bp = (w == 0) ? bq : (w == 1) ? bk : bv;
    ushort_t* OH = (w == 0) ? Qh : (w == 1) ? Kh : Vth;
    ushort_t* OL = (w == 0) ? Ql : (w == 1) ? Kl : Vtl;
    const ushort_t* Wh = wth + ((size_t)w * Hn + h) * En * Dn;   // [64][768]
    const ushort_t* Wl = wtl + ((size_t)w * Hn + h) * En * Dn;

    __shared__ __align__(16) ushort_t Ah[128 * 64];
    __shared__ __align__(16) ushort_t Al[128 * 64];
    __shared__ __align__(16) ushort_t Bh[64 * 64];
    __shared__ __align__(16) ushort_t Bl[64 * 64];

    const int tid  = threadIdx.x;
    const int lane = tid & 63;
    const int lr   = lane & 15, lg = lane >> 4;
    const int wid  = tid >> 6;
    const int wm   = wid >> 1;   // 0..1 : 64-row half
    const int wn   = wid & 1;    // 0..1 : 32-col half
    const int m0   = mt * 128;

    f32x4 acc[4][2] = {};

    for (int k0 = 0; k0 < Dn; k0 += 64) {
        if (k0) __syncthreads();
        #pragma unroll
        for (int t = 0; t < 4; ++t) {        // A hi/lo: 1024 chunks each
            int c = tid + t * 256;
            int r = c >> 3, sl = (c & 7) ^ (r & 7);
            size_t go = (size_t)(m0 + r) * Dn + k0 + sl * 8;
            GLL16(xh + go, &Ah[c * 8]);
            GLL16(xl + go, &Al[c * 8]);
        }
        #pragma unroll
        for (int t = 0; t < 2; ++t) {        // B hi/lo: 512 chunks each
            int c = tid + t * 256;
            int r = c >> 3, sl = (c & 7) ^ (r & 7);
            size_t go = (size_t)r * Dn + k0 + sl * 8;
            GLL16(Wh + go, &Bh[c * 8]);
            GLL16(Wl + go, &Bl[c * 8]);
        }
        __syncthreads();

        #pragma unroll
        for (int ks = 0; ks < 2; ++ks) {
            const int kb = ks * 32 + lg * 8;
            bf16x8 a_h[4], a_l[4], b_h[2], b_l[2];
            #pragma unroll
            for (int i = 0; i < 4; ++i) {
                int row = wm * 64 + i * 16 + lr;
                int ai = (row * 64 + kb) ^ ((row & 7) << 3);
                a_h[i] = *(const bf16x8*)&Ah[ai];
                a_l[i] = *(const bf16x8*)&Al[ai];
            }
            #pragma unroll
            for (int j = 0; j < 2; ++j) {
                int col = wn * 32 + j * 16 + lr;
                int bi = (col * 64 + kb) ^ ((col & 7) << 3);
                b_h[j] = *(const bf16x8*)&Bh[bi];
                b_l[j] = *(const bf16x8*)&Bl[bi];
            }
            #pragma unroll
            for (int i = 0; i < 4; ++i)
                #pragma unroll
                for (int j = 0; j < 2; ++j) {
                    acc[i][j] = MFMA(a_h[i], b_h[j], acc[i][j]);
                    acc[i][j] = MFMA(a_l[i], b_h[j], acc[i][j]);
                    acc[i][j] = MFMA(a_h[i], b_l[j], acc[i][j]);
                }
        }
    }

    // epilogue: C/D layout col=lane&15, row=(lane>>4)*4+r
    #pragma unroll
    for (int j = 0; j < 2; ++j) {
        int col = wn * 32 + j * 16 + lr;
        float bb = bp[h * En + col];
        #pragma unroll
        for (int i = 0; i < 4; ++i) {
            #pragma unroll
            for (int r = 0; r < 4; ++r) {
                int m = m0 + wm * 64 + i * 16 + lg * 4 + r;
                int bidx = m >> 10, s = m & 1023;
                float v = acc[i][j][r] + bb;
                ushort_t vh = bf_hi(v);
                ushort_t vl = bf_hi(v - bf_f(vh));
                size_t off;
                if (w < 2)   // [bh][s][e]
                    off = (size_t)((bidx * Hn + h) * Sn + s) * En + col;
                else         // V transposed: [bh][e][s]
                    off = (size_t)((bidx * Hn + h) * En + col) * Sn + s;
                OH[off] = vh;
                OL[off] = vl;
            }
        }
    }
}

// ---------------------------------------------------------------------------
// Kernel 2: fused scores+softmax+probs+PV, 32x32x16 MFMA, q-tile 128.
// 4 waves x 32 q-rows.  Pass 1: rowsums of exp(S/8) (128-key staging rounds).
// Pass 2: recompute S, write f32 probs, P(bf16-hi) -> LDS, PV = mfma(Vt, P^T)
// giving ctx^T with contiguous-e epilogue.
// A-frag (32x32x16): row=lane&31, k=(lane>>5)*8+j.  B-frag: col=lane&31, same k.
// C/D: col=lane&31, row=(reg&3)+8*(reg>>2)+4*(lane>>5)   [m74/m101]
// ---------------------------------------------------------------------------
__global__ __launch_bounds__(256, 3) void attn_kernel(
    const ushort_t* __restrict__ Qh, const ushort_t* __restrict__ Ql,
    const ushort_t* __restrict__ Kh_g, const ushort_t* __restrict__ Kl_g,
    const ushort_t* __restrict__ Vth_g, const ushort_t* __restrict__ Vtl_g,
    float* __restrict__ Pr,
    ushort_t* __restrict__ CTXh, ushort_t* __restrict__ CTXl)
{
    const int qt = blockIdx.x;    // 0..7 (128 q-rows)
    const int bh = blockIdx.y;    // 0..95
    const int bb = bh / Hn, h = bh % Hn;

    // KV[0]=K_hi, KV[1]=K_lo, KV[2]=V_hi, KV[3]=V_lo  (each [row][64] swz)
    __shared__ __align__(16) ushort_t KV[4][64 * 64];   // 32 KB
    __shared__ __align__(16) ushort_t Ps[128 * 64];     // 16 KB (P hi only)

    const int tid = threadIdx.x, lane = tid & 63, w = tid >> 6;
    const int l31 = lane & 31, lh = lane >> 5;

    const ushort_t* KH  = Kh_g  + (size_t)bh * Sn * En;   // [s][e]
    const ushort_t* KL  = Kl_g  + (size_t)bh * Sn * En;
    const ushort_t* VTH = Vth_g + (size_t)bh * En * Sn;   // [e][s]
    const ushort_t* VTL = Vtl_g + (size_t)bh * En * Sn;

    // Q fragments: q-row = qt*128 + w*32 + l31, k-chunk kc*16 + lh*8
    bf16x8 qh[4], ql[4];
    {
        size_t off = ((size_t)bh * Sn + qt * 128 + w * 32 + l31) * En + lh * 8;
        #pragma unroll
        for (int kc = 0; kc < 4; ++kc) {
            qh[kc] = *(const bf16x8*)&Qh[off + kc * 16];
            ql[kc] = *(const bf16x8*)&Ql[off + kc * 16];
        }
    }

    float rs[16];
    #pragma unroll
    for (int i = 0; i < 16; ++i) rs[i] = 0.f;

    // ---- pass 1: rowsums, 8 rounds x 128 keys ----
    for (int kr = 0; kr < 8; ++kr) {
        __syncthreads();
        #pragma unroll
        for (int t = 0; t < 2; ++t) {
            int c = tid + t * 256;              // 0..511
            int r = c >> 3, sl = (c & 7) ^ (r & 7);
            size_t g0 = (size_t)(kr * 128 + r) * En + sl * 8;
            size_t g1 = (size_t)(kr * 128 + 64 + r) * En + sl * 8;
            GLL16(KH + g0, &KV[0][c * 8]);
            GLL16(KL + g0, &KV[1][c * 8]);
            GLL16(KH + g1, &KV[2][c * 8]);
            GLL16(KL + g1, &KV[3][c * 8]);
        }
        __syncthreads();

        #pragma unroll
        for (int kt = 0; kt < 4; ++kt) {
            const ushort_t* bhp = KV[(kt >> 1) * 2];
            const ushort_t* blp = KV[(kt >> 1) * 2 + 1];
            int krow = (kt & 1) * 32 + l31;
            f32x16 sacc = {};
            #pragma unroll
            for (int kc = 0; kc < 4; ++kc) {
                int bi = (krow * 64 + kc * 16 + lh * 8) ^ ((krow & 7) << 3);
                bf16x8 kh = *(const bf16x8*)&bhp[bi];
                bf16x8 kl = *(const bf16x8*)&blp[bi];
                sacc = MFMA32(qh[kc], kh, sacc);
                sacc = MFMA32(ql[kc], kh, sacc);
                sacc = MFMA32(qh[kc], kl, sacc);
            }
            #pragma unroll
            for (int rg = 0; rg < 16; ++rg)
                rs[rg] += __expf(0.125f * sacc[rg]);
        }
    }
    // reduce across the 32 key-lanes within each half; rs -> 1/rowsum
    #pragma unroll
    for (int rg = 0; rg < 16; ++rg) {
        float v = rs[rg];
        v += __shfl_xor(v, 1);
        v += __shfl_xor(v, 2);
        v += __shfl_xor(v, 4);
        v += __shfl_xor(v, 8);
        v += __shfl_xor(v, 16);
        rs[rg] = 1.f / v;
    }

    // ---- pass 2: recompute, write probs, PV ----
    f32x16 cacc[2] = {};
    float* PrB = Pr + ((size_t)bh * Sn + qt * 128 + w * 32) * Sn;

    for (int kt = 0; kt < 16; ++kt) {
        __syncthreads();
        #pragma unroll
        for (int t = 0; t < 2; ++t) {
            int c = tid + t * 256;              // 0..511
            int r = c >> 3, sl = (c & 7) ^ (r & 7);
            size_t gk = (size_t)(kt * 64 + r) * En + sl * 8;
            size_t gv = (size_t)r * Sn + kt * 64 + sl * 8;
            GLL16(KH + gk, &KV[0][c * 8]);
            GLL16(KL + gk, &KV[1][c * 8]);
            GLL16(VTH + gv, &KV[2][c * 8]);
            GLL16(VTL + gv, &KV[3][c * 8]);
        }
        __syncthreads();

        // QK^T: 2 key tiles of 32, identical op order to pass 1
        #pragma unroll
        for (int ktile = 0; ktile < 2; ++ktile) {
            int krow = ktile * 32 + l31;
            f32x16 sacc = {};
            #pragma unroll
            for (int kc = 0; kc < 4; ++kc) {
                int bi = (krow * 64 + kc * 16 + lh * 8) ^ ((krow & 7) << 3);
                bf16x8 kh = *(const bf16x8*)&KV[0][bi];
                bf16x8 kl = *(const bf16x8*)&KV[1][bi];
                sacc = MFMA32(qh[kc], kh, sacc);
                sacc = MFMA32(ql[kc], kh, sacc);
                sacc = MFMA32(qh[kc], kl, sacc);
            }
            // normalize, write probs (f32), stash P hi in swizzled LDS
            #pragma unroll
            for (int rg = 0; rg < 16; ++rg) {
                int qloc = (rg & 3) + 8 * (rg >> 2) + 4 * lh;   // 0..31
                float p = __expf(0.125f * sacc[rg]) * rs[rg];
                PrB[(size_t)qloc * Sn + kt * 64 + ktile * 32 + l31] = p;
                int pi = ((w * 32 + qloc) * 64 + ktile * 32 + l31)
                         ^ ((qloc & 7) << 3);
                Ps[pi] = bf_hi(p);
            }
        }

        // PV: ctx^T += Vt-frag x P^T-frag   (own wave's P rows only)
        #pragma unroll
        for (int kc = 0; kc < 4; ++kc) {
            int bi2 = ((w * 32 + l31) * 64 + kc * 16 + lh * 8)
                      ^ ((l31 & 7) << 3);
            bf16x8 pb = *(const bf16x8*)&Ps[bi2];
            #pragma unroll
            for (int et = 0; et < 2; ++et) {
                int vrow = et * 32 + l31;
                int ai = (vrow * 64 + kc * 16 + lh * 8) ^ ((vrow & 7) << 3);
                bf16x8 vh = *(const bf16x8*)&KV[2][ai];
                bf16x8 vl = *(const bf16x8*)&KV[3][ai];
                cacc[et] = MFMA32(vh, pb, cacc[et]);
                cacc[et] = MFMA32(vl, pb, cacc[et]);
            }
        }
    }

    // epilogue: ctx^T -> CTX [b][s][h*64+e], lane owns row s, e contiguous x4
    {
        int s = qt * 128 + w * 32 + l31;
        size_t base = ((size_t)bb * Sn + s) * Dn + h * En;
        #pragma unroll
        for (int et = 0; et < 2; ++et) {
            #pragma unroll
            for (int rg = 0; rg < 4; ++rg) {
                int e0 = et * 32 + rg * 8 + 4 * lh;
                ushort_t hv[4], lv[4];
                #pragma unroll
                for (int i = 0; i < 4; ++i) {
                    float v = cacc[et][rg * 4 + i];
                    hv[i] = bf_hi(v);
                    lv[i] = bf_hi(v - bf_f(hv[i]));
                }
                *(ushort4*)&CTXh[base + e0] =
                    make_ushort4(hv[0], hv[1], hv[2], hv[3]);
                *(ushort4*)&CTXl[base + e0] =
                    make_ushort4(lv[0], lv[1], lv[2], lv[3]);
            }
        }
    }
}

// ---------------------------------------------------------------------------
// Kernel 3: out = CTX @ Wo^T + bo via bf16x3 MFMA.
// ---------------------------------------------------------------------------
__global__ __launch_bounds__(256) void out_mfma_kernel(
    const ushort_t* __restrict__ CTXh, const ushort_t* __restrict__ CTXl,
    const float* __restrict__ Wo, const float* __restrict__ bo,
    float* __restrict__ out)
{
    const int mt = blockIdx.x;   // 0..63
    const int nt = blockIdx.y;   // 0..11

    __shared__ __align__(16) ushort_t Ah[128 * 64];
    __shared__ __align__(16) ushort_t Al[128 * 64];
    __shared__ __align__(16) ushort_t Bh[64 * 64];
    __shared__ __align__(16) ushort_t Bl[64 * 64];

    const int tid  = threadIdx.x;
    const int lane = tid & 63;
    const int lr   = lane & 15, lg = lane >> 4;
    const int wid  = tid >> 6;
    const int wm   = wid >> 1, wn = wid & 1;
    const int m0   = mt * 128, n0 = nt * 64;

    f32x4 acc[4][2] = {};

    for (int k0 = 0; k0 < Dn; k0 += 64) {
        if (k0) __syncthreads();
        #pragma unroll
        for (int t = 0; t < 4; ++t) {
            int c = tid + t * 256;
            int r = c >> 3, sl = (c & 7) ^ (r & 7);
            size_t go = (size_t)(m0 + r) * Dn + k0 + sl * 8;
            GLL16(CTXh + go, &Ah[c * 8]);
            GLL16(CTXl + go, &Al[c * 8]);
        }
        // B: load Wo f32, split to hi/lo bf16, swizzled LDS write
        #pragma unroll
        for (int t = 0; t < 4; ++t) {
            int idx = tid + t * 256;          // 0..1023 float4-quads
            int n = idx >> 4, f4 = idx & 15;
            float4 f = *(const float4*)&Wo[(size_t)(n0 + n) * Dn + k0 + f4 * 4];
            ushort_t h0 = bf_hi(f.x), h1 = bf_hi(f.y);
            ushort_t h2 = bf_hi(f.z), h3 = bf_hi(f.w);
            unsigned int hi0 = (unsigned)h0 | ((unsigned)h1 << 16);
            unsigned int hi1 = (unsigned)h2 | ((unsigned)h3 << 16);
            unsigned int lo0 = (unsigned)bf_hi(f.x - bf_f(h0)) |
                               ((unsigned)bf_hi(f.y - bf_f(h1)) << 16);
            unsigned int lo1 = (unsigned)bf_hi(f.z - bf_f(h2)) |
                               ((unsigned)bf_hi(f.w - bf_f(h3)) << 16);
            int di = (n * 64 + f4 * 4) ^ ((n & 7) << 3);
            *(uint2*)&Bh[di] = make_uint2(hi0, hi1);
            *(uint2*)&Bl[di] = make_uint2(lo0, lo1);
        }
        __syncthreads();

        #pragma unroll
        for (int ks = 0; ks < 2; ++ks) {
            const int kb = ks * 32 + lg * 8;
            bf16x8 a_h[4], a_l[4], b_h[2], b_l[2];
            #pragma unroll
            for (int i = 0; i < 4; ++i) {
                int row = wm * 64 + i * 16 + lr;
                int ai = (row * 64 + kb) ^ ((row & 7) << 3);
                a_h[i] = *(const bf16x8*)&Ah[ai];
                a_l[i] = *(const bf16x8*)&Al[ai];
            }
            #pragma unroll
            for (int j = 0; j < 2; ++j) {
                int col = wn * 32 + j * 16 + lr;
                int bi = (col * 64 + kb) ^ ((col & 7) << 3);
                b_h[j] = *(const bf16x8*)&Bh[bi];
                b_l[j] = *(const bf16x8*)&Bl[bi];
            }
            #pragma unroll
            for (int i = 0; i < 4; ++i)
                #pragma unroll
                for (int j = 0; j < 2; ++j) {
                    acc[i][j] = MFMA(a_h[i], b_h[j], acc[i][j]);
                    acc[i][j] = MFMA(a_l[i], b_h[j], acc[i][j]);
                    acc[i][j] = MFMA(a_h[i], b_l[j], acc[i][j]);
                }
        }
    }

    #pragma unroll
    for (int j = 0; j < 2; ++j) {
        int col = n0 + wn * 32 + j * 16 + lr;
        float bb = bo[col];
        #pragma unroll
        for (int i = 0; i < 4; ++i)
            #pragma unroll
            for (int r = 0; r < 4; ++r) {
                int m = m0 + wm * 64 + i * 16 + lg * 4 + r;
                out[(size_t)m * Dn + col] = acc[i][j][r] + bb;
            }
    }
}

// ---------------------------------------------------------------------------
extern "C" void kernel_launch(void* const* d_in, const int* in_sizes, int n_in,
                              void* d_out, int out_size, void* d_ws, size_t ws_size,
                              hipStream_t stream)
{
    const float* x  = (const float*)d_in[0];
    const float* Wq = (const float*)d_in[1];
    const float* bq = (const float*)d_in[2];
    const float* Wk = (const float*)d_in[3];
    const float* bk = (const float*)d_in[4];
    const float* Wv = (const float*)d_in[5];
    const float* bv = (const float*)d_in[6];
    const float* Wo = (const float*)d_in[7];
    const float* bo = (const float*)d_in[8];

    float* out = (float*)d_out;
    const size_t QSZ = (size_t)Bn * Hn * Sn * En;      // 6,291,456 elements
    float* probs = out + (size_t)Bn * Sn * Dn;         // probs region of d_out

    // ws layout (ushort arrays, total = old 4*QSZ float footprint):
    ushort_t* u   = (ushort_t*)d_ws;
    ushort_t* Qh  = u;
    ushort_t* Ql  = Qh + QSZ;
    ushort_t* Kh  = Ql + QSZ;
    ushort_t* Kl  = Kh + QSZ;
    ushort_t* Vth = Kl + QSZ;
    ushort_t* Vtl = Vth + QSZ;
    ushort_t* xh  = Vtl + QSZ;          // dead after qkv ...
    ushort_t* xl  = xh + (size_t)Mn * Dn;
    ushort_t* CTXh = xh;                // ... reused as CTX hi/lo
    ushort_t* CTXl = xl;

    // QKV weight splits live at the head of the probs region (dead before
    // attn_kernel overwrites all of probs).
    ushort_t* wth = (ushort_t*)probs;
    ushort_t* wtl = wth + (size_t)3 * Hn * En * Dn;

    split_x_kernel<<<dim3(Mn * Dn / 4 / 256), 256, 0, stream>>>(
        (const float4*)x, xh, xl);

    split_w_kernel<<<dim3(Dn / 64, Hn, 3), 256, 0, stream>>>(
        Wq, Wk, Wv, wth, wtl);

    qkv_mfma_kernel<<<dim3(Mn / 128, Hn, 3), 256, 0, stream>>>(
        xh, xl, wth, wtl, bq, bk, bv, Qh, Ql, Kh, Kl, Vth, Vtl);

    attn_kernel<<<dim3(Sn / 128, Bn * Hn), 256, 0, stream>>>(
        Qh, Ql, Kh, Kl, Vth, Vtl, probs, CTXh, CTXl);

    out_mfma_kernel<<<dim3(Mn / 128, Dn / 64), 256, 0, stream>>>(
        CTXh, CTXl, Wo, bo, out);
}

// Round 5
// 802.375 us; speedup vs baseline: 1.0302x; 1.0302x over previous
//
#include <hip/hip_runtime.h>
#include <cstddef>

// Problem constants
#define Bn 8
#define Sn 1024
#define Hn 12
#define Dn 768
#define En 64          // head dim
#define Mn (Bn * Sn)   // 8192 rows

typedef unsigned short ushort_t;
typedef __attribute__((ext_vector_type(4))) float f32x4;
typedef __attribute__((ext_vector_type(16))) float f32x16;
typedef __bf16 bf16x8 __attribute__((ext_vector_type(8)));

#define MFMA(a, b, c)   __builtin_amdgcn_mfma_f32_16x16x32_bf16(a, b, c, 0, 0, 0)
#define MFMA32(a, b, c) __builtin_amdgcn_mfma_f32_32x32x16_bf16(a, b, c, 0, 0, 0)

// RNE f32 -> bf16 (inputs finite; NaN not handled)
__device__ __forceinline__ ushort_t bf_hi(float f) {
    unsigned int u = __float_as_uint(f);
    return (ushort_t)((u + 0x7FFF + ((u >> 16) & 1)) >> 16);
}
__device__ __forceinline__ float bf_f(ushort_t s) {
    return __uint_as_float(((unsigned int)s) << 16);
}

// global -> LDS direct copy, 16B per lane
#define GLL16(gp, lp)                                                        \
    __builtin_amdgcn_global_load_lds(                                        \
        (__attribute__((address_space(1))) void*)(gp),                       \
        (__attribute__((address_space(3))) void*)(lp), 16, 0, 0)

// ---------------------------------------------------------------------------
// Pre-pass A: split x [8192][768] f32 into hi/lo bf16 (same layout).
// ---------------------------------------------------------------------------
__global__ __launch_bounds__(256) void split_x_kernel(
    const float4* __restrict__ x4,
    ushort_t* __restrict__ xh, ushort_t* __restrict__ xl)
{
    int idx = blockIdx.x * 256 + threadIdx.x;   // 0 .. 1572863
    float4 f = x4[idx];
    ushort_t h0 = bf_hi(f.x), h1 = bf_hi(f.y), h2 = bf_hi(f.z), h3 = bf_hi(f.w);
    ushort_t l0 = bf_hi(f.x - bf_f(h0));
    ushort_t l1 = bf_hi(f.y - bf_f(h1));
    ushort_t l2 = bf_hi(f.z - bf_f(h2));
    ushort_t l3 = bf_hi(f.w - bf_f(h3));
    *(ushort4*)&xh[(size_t)idx * 4] = make_ushort4(h0, h1, h2, h3);
    *(ushort4*)&xl[(size_t)idx * 4] = make_ushort4(l0, l1, l2, l3);
}

// ---------------------------------------------------------------------------
// Pre-pass B: split + transpose W[h][d][e] -> Wt[w][h][e][d] hi/lo bf16.
// ---------------------------------------------------------------------------
__global__ __launch_bounds__(256) void split_w_kernel(
    const float* __restrict__ Wq, const float* __restrict__ Wk,
    const float* __restrict__ Wv,
    ushort_t* __restrict__ wth, ushort_t* __restrict__ wtl)
{
    const int dt = blockIdx.x;   // 0..11 (64-wide d tile)
    const int h  = blockIdx.y;   // 0..11
    const int w  = blockIdx.z;   // 0..2
    const float* Wp = (w == 0) ? Wq : (w == 1) ? Wk : Wv;

    __shared__ float Ws[64][65];
    const int tid = threadIdx.x;

    #pragma unroll
    for (int t = 0; t < 16; ++t) {
        int idx = tid + t * 256;          // 0..4095
        int d = idx >> 6, e = idx & 63;
        Ws[d][e] = Wp[((size_t)h * Dn + dt * 64 + d) * En + e];
    }
    __syncthreads();

    ushort_t* oh = wth + ((size_t)w * Hn + h) * En * Dn;
    ushort_t* ol = wtl + ((size_t)w * Hn + h) * En * Dn;
    #pragma unroll
    for (int t = 0; t < 16; ++t) {
        int idx = tid + t * 256;
        int e = idx >> 6, dd = idx & 63;
        float f = Ws[dd][e];
        ushort_t hi = bf_hi(f);
        oh[(size_t)e * Dn + dt * 64 + dd] = hi;
        ol[(size_t)e * Dn + dt * 64 + dd] = bf_hi(f - bf_f(hi));
    }
}

// ---------------------------------------------------------------------------
// Kernel 1: QKV projection via bf16x3 MFMA.  Outputs bf16 hi/lo directly:
//   Q,K: [bh][s][e];  V transposed: [bh][e][s]  (PV A-operand layout).
// Tile 128(m) x 64(e), BK=64.  LDS XOR-swizzled (^((row&7)<<3) ushort idx).
// ---------------------------------------------------------------------------
__global__ __launch_bounds__(256) void qkv_mfma_kernel(
    const ushort_t* __restrict__ xh, const ushort_t* __restrict__ xl,
    const ushort_t* __restrict__ wth, const ushort_t* __restrict__ wtl,
    const float* __restrict__ bq, const float* __restrict__ bk,
    const float* __restrict__ bv,
    ushort_t* __restrict__ Qh, ushort_t* __restrict__ Ql,
    ushort_t* __restrict__ Kh, ushort_t* __restrict__ Kl,
    ushort_t* __restrict__ Vth, ushort_t* __restrict__ Vtl)
{
    const int mt = blockIdx.x;   // 0..63
    const int h  = blockIdx.y;   // 0..11
    const int w  = blockIdx.z;   // 0..2
    const float* bp = (w == 0) ? bq : (w == 1) ? bk : bv;
    ushort_t* OH = (w == 0) ? Qh : (w == 1) ? Kh : Vth;
    ushort_t* OL = (w == 0) ? Ql : (w == 1) ? Kl : Vtl;
    const ushort_t* Wh = wth + ((size_t)w * Hn + h) * En * Dn;   // [64][768]
    const ushort_t* Wl = wtl + ((size_t)w * Hn + h) * En * Dn;

    __shared__ __align__(16) ushort_t Ah[128 * 64];
    __shared__ __align__(16) ushort_t Al[128 * 64];
    __shared__ __align__(16) ushort_t Bh[64 * 64];
    __shared__ __align__(16) ushort_t Bl[64 * 64];

    const int tid  = threadIdx.x;
    const int lane = tid & 63;
    const int lr   = lane & 15, lg = lane >> 4;
    const int wid  = tid >> 6;
    const int wm   = wid >> 1;   // 0..1 : 64-row half
    const int wn   = wid & 1;    // 0..1 : 32-col half
    const int m0   = mt * 128;

    f32x4 acc[4][2] = {};

    for (int k0 = 0; k0 < Dn; k0 += 64) {
        if (k0) __syncthreads();
        #pragma unroll
        for (int t = 0; t < 4; ++t) {        // A hi/lo: 1024 chunks each
            int c = tid + t * 256;
            int r = c >> 3, sl = (c & 7) ^ (r & 7);
            size_t go = (size_t)(m0 + r) * Dn + k0 + sl * 8;
            GLL16(xh + go, &Ah[c * 8]);
            GLL16(xl + go, &Al[c * 8]);
        }
        #pragma unroll
        for (int t = 0; t < 2; ++t) {        // B hi/lo: 512 chunks each
            int c = tid + t * 256;
            int r = c >> 3, sl = (c & 7) ^ (r & 7);
            size_t go = (size_t)r * Dn + k0 + sl * 8;
            GLL16(Wh + go, &Bh[c * 8]);
            GLL16(Wl + go, &Bl[c * 8]);
        }
        __syncthreads();

        #pragma unroll
        for (int ks = 0; ks < 2; ++ks) {
            const int kb = ks * 32 + lg * 8;
            bf16x8 a_h[4], a_l[4], b_h[2], b_l[2];
            #pragma unroll
            for (int i = 0; i < 4; ++i) {
                int row = wm * 64 + i * 16 + lr;
                int ai = (row * 64 + kb) ^ ((row & 7) << 3);
                a_h[i] = *(const bf16x8*)&Ah[ai];
                a_l[i] = *(const bf16x8*)&Al[ai];
            }
            #pragma unroll
            for (int j = 0; j < 2; ++j) {
                int col = wn * 32 + j * 16 + lr;
                int bi = (col * 64 + kb) ^ ((col & 7) << 3);
                b_h[j] = *(const bf16x8*)&Bh[bi];
                b_l[j] = *(const bf16x8*)&Bl[bi];
            }
            #pragma unroll
            for (int i = 0; i < 4; ++i)
                #pragma unroll
                for (int j = 0; j < 2; ++j) {
                    acc[i][j] = MFMA(a_h[i], b_h[j], acc[i][j]);
                    acc[i][j] = MFMA(a_l[i], b_h[j], acc[i][j]);
                    acc[i][j] = MFMA(a_h[i], b_l[j], acc[i][j]);
                }
        }
    }

    // epilogue: C/D layout col=lane&15, row=(lane>>4)*4+r
    #pragma unroll
    for (int j = 0; j < 2; ++j) {
        int col = wn * 32 + j * 16 + lr;
        float bb = bp[h * En + col];
        #pragma unroll
        for (int i = 0; i < 4; ++i) {
            #pragma unroll
            for (int r = 0; r < 4; ++r) {
                int m = m0 + wm * 64 + i * 16 + lg * 4 + r;
                int bidx = m >> 10, s = m & 1023;
                float v = acc[i][j][r] + bb;
                ushort_t vh = bf_hi(v);
                ushort_t vl = bf_hi(v - bf_f(vh));
                size_t off;
                if (w < 2)   // [bh][s][e]
                    off = (size_t)((bidx * Hn + h) * Sn + s) * En + col;
                else         // V transposed: [bh][e][s]
                    off = (size_t)((bidx * Hn + h) * En + col) * Sn + s;
                OH[off] = vh;
                OL[off] = vl;
            }
        }
    }
}

// ---------------------------------------------------------------------------
// Kernel 2: fused scores+softmax+probs+PV, 32x32x16 MFMA, q-tile 128.
// 1D grid 768, XCD-pinned: all 8 q-tiles of a bh land on one XCD (L2 reuse).
// Probs written with non-temporal stores (never re-read on device) so the
// 402 MB stream doesn't evict K/V from L2/L3.
// ---------------------------------------------------------------------------
__global__ __launch_bounds__(256, 3) void attn_kernel(
    const ushort_t* __restrict__ Qh, const ushort_t* __restrict__ Ql,
    const ushort_t* __restrict__ Kh_g, const ushort_t* __restrict__ Kl_g,
    const ushort_t* __restrict__ Vth_g, const ushort_t* __restrict__ Vtl_g,
    float* __restrict__ Pr,
    ushort_t* __restrict__ CTXh, ushort_t* __restrict__ CTXl)
{
    // XCD-pinning decode: id%8 = XCD (round-robin dispatch heuristic).
    const int id  = blockIdx.x;          // 0..767
    const int xcd = id & 7, idx = id >> 3;
    const int bh  = xcd + 8 * (idx % 12);  // 0..95, bh&7 == xcd
    const int qt  = idx / 12;              // 0..7
    const int bb = bh / Hn, h = bh % Hn;

    // KV[0]=K_hi, KV[1]=K_lo, KV[2]=V_hi, KV[3]=V_lo  (each [row][64] swz)
    __shared__ __align__(16) ushort_t KV[4][64 * 64];   // 32 KB
    __shared__ __align__(16) ushort_t Ps[128 * 64];     // 16 KB (P hi only)

    const int tid = threadIdx.x, lane = tid & 63, w = tid >> 6;
    const int l31 = lane & 31, lh = lane >> 5;

    const ushort_t* KH  = Kh_g  + (size_t)bh * Sn * En;   // [s][e]
    const ushort_t* KL  = Kl_g  + (size_t)bh * Sn * En;
    const ushort_t* VTH = Vth_g + (size_t)bh * En * Sn;   // [e][s]
    const ushort_t* VTL = Vtl_g + (size_t)bh * En * Sn;

    // Q fragments: q-row = qt*128 + w*32 + l31, k-chunk kc*16 + lh*8
    bf16x8 qh[4], ql[4];
    {
        size_t off = ((size_t)bh * Sn + qt * 128 + w * 32 + l31) * En + lh * 8;
        #pragma unroll
        for (int kc = 0; kc < 4; ++kc) {
            qh[kc] = *(const bf16x8*)&Qh[off + kc * 16];
            ql[kc] = *(const bf16x8*)&Ql[off + kc * 16];
        }
    }

    float rs[16];
    #pragma unroll
    for (int i = 0; i < 16; ++i) rs[i] = 0.f;

    // ---- pass 1: rowsums, 8 rounds x 128 keys ----
    for (int kr = 0; kr < 8; ++kr) {
        __syncthreads();
        #pragma unroll
        for (int t = 0; t < 2; ++t) {
            int c = tid + t * 256;              // 0..511
            int r = c >> 3, sl = (c & 7) ^ (r & 7);
            size_t g0 = (size_t)(kr * 128 + r) * En + sl * 8;
            size_t g1 = (size_t)(kr * 128 + 64 + r) * En + sl * 8;
            GLL16(KH + g0, &KV[0][c * 8]);
            GLL16(KL + g0, &KV[1][c * 8]);
            GLL16(KH + g1, &KV[2][c * 8]);
            GLL16(KL + g1, &KV[3][c * 8]);
        }
        __syncthreads();

        #pragma unroll
        for (int kt = 0; kt < 4; ++kt) {
            const ushort_t* bhp = KV[(kt >> 1) * 2];
            const ushort_t* blp = KV[(kt >> 1) * 2 + 1];
            int krow = (kt & 1) * 32 + l31;
            f32x16 sacc = {};
            #pragma unroll
            for (int kc = 0; kc < 4; ++kc) {
                int bi = (krow * 64 + kc * 16 + lh * 8) ^ ((krow & 7) << 3);
                bf16x8 kh = *(const bf16x8*)&bhp[bi];
                bf16x8 kl = *(const bf16x8*)&blp[bi];
                sacc = MFMA32(qh[kc], kh, sacc);
                sacc = MFMA32(ql[kc], kh, sacc);
                sacc = MFMA32(qh[kc], kl, sacc);
            }
            #pragma unroll
            for (int rg = 0; rg < 16; ++rg)
                rs[rg] += __expf(0.125f * sacc[rg]);
        }
    }
    // reduce across the 32 key-lanes within each half; rs -> 1/rowsum
    #pragma unroll
    for (int rg = 0; rg < 16; ++rg) {
        float v = rs[rg];
        v += __shfl_xor(v, 1);
        v += __shfl_xor(v, 2);
        v += __shfl_xor(v, 4);
        v += __shfl_xor(v, 8);
        v += __shfl_xor(v, 16);
        rs[rg] = 1.f / v;
    }

    // ---- pass 2: recompute, write probs (non-temporal), PV ----
    f32x16 cacc[2] = {};
    float* PrB = Pr + ((size_t)bh * Sn + qt * 128 + w * 32) * Sn;

    for (int kt = 0; kt < 16; ++kt) {
        __syncthreads();
        #pragma unroll
        for (int t = 0; t < 2; ++t) {
            int c = tid + t * 256;              // 0..511
            int r = c >> 3, sl = (c & 7) ^ (r & 7);
            size_t gk = (size_t)(kt * 64 + r) * En + sl * 8;
            size_t gv = (size_t)r * Sn + kt * 64 + sl * 8;
            GLL16(KH + gk, &KV[0][c * 8]);
            GLL16(KL + gk, &KV[1][c * 8]);
            GLL16(VTH + gv, &KV[2][c * 8]);
            GLL16(VTL + gv, &KV[3][c * 8]);
        }
        __syncthreads();

        // QK^T: 2 key tiles of 32, identical op order to pass 1
        #pragma unroll
        for (int ktile = 0; ktile < 2; ++ktile) {
            int krow = ktile * 32 + l31;
            f32x16 sacc = {};
            #pragma unroll
            for (int kc = 0; kc < 4; ++kc) {
                int bi = (krow * 64 + kc * 16 + lh * 8) ^ ((krow & 7) << 3);
                bf16x8 kh = *(const bf16x8*)&KV[0][bi];
                bf16x8 kl = *(const bf16x8*)&KV[1][bi];
                sacc = MFMA32(qh[kc], kh, sacc);
                sacc = MFMA32(ql[kc], kh, sacc);
                sacc = MFMA32(qh[kc], kl, sacc);
            }
            // normalize, write probs (NT f32), stash P hi in swizzled LDS
            #pragma unroll
            for (int rg = 0; rg < 16; ++rg) {
                int qloc = (rg & 3) + 8 * (rg >> 2) + 4 * lh;   // 0..31
                float p = __expf(0.125f * sacc[rg]) * rs[rg];
                __builtin_nontemporal_store(
                    p, &PrB[(size_t)qloc * Sn + kt * 64 + ktile * 32 + l31]);
                int pi = ((w * 32 + qloc) * 64 + ktile * 32 + l31)
                         ^ ((qloc & 7) << 3);
                Ps[pi] = bf_hi(p);
            }
        }

        // PV: ctx^T += Vt-frag x P^T-frag   (own wave's P rows only)
        #pragma unroll
        for (int kc = 0; kc < 4; ++kc) {
            int bi2 = ((w * 32 + l31) * 64 + kc * 16 + lh * 8)
                      ^ ((l31 & 7) << 3);
            bf16x8 pb = *(const bf16x8*)&Ps[bi2];
            #pragma unroll
            for (int et = 0; et < 2; ++et) {
                int vrow = et * 32 + l31;
                int ai = (vrow * 64 + kc * 16 + lh * 8) ^ ((vrow & 7) << 3);
                bf16x8 vh = *(const bf16x8*)&KV[2][ai];
                bf16x8 vl = *(const bf16x8*)&KV[3][ai];
                cacc[et] = MFMA32(vh, pb, cacc[et]);
                cacc[et] = MFMA32(vl, pb, cacc[et]);
            }
        }
    }

    // epilogue: ctx^T -> CTX [b][s][h*64+e], lane owns row s, e contiguous x4
    {
        int s = qt * 128 + w * 32 + l31;
        size_t base = ((size_t)bb * Sn + s) * Dn + h * En;
        #pragma unroll
        for (int et = 0; et < 2; ++et) {
            #pragma unroll
            for (int rg = 0; rg < 4; ++rg) {
                int e0 = et * 32 + rg * 8 + 4 * lh;
                ushort_t hv[4], lv[4];
                #pragma unroll
                for (int i = 0; i < 4; ++i) {
                    float v = cacc[et][rg * 4 + i];
                    hv[i] = bf_hi(v);
                    lv[i] = bf_hi(v - bf_f(hv[i]));
                }
                *(ushort4*)&CTXh[base + e0] =
                    make_ushort4(hv[0], hv[1], hv[2], hv[3]);
                *(ushort4*)&CTXl[base + e0] =
                    make_ushort4(lv[0], lv[1], lv[2], lv[3]);
            }
        }
    }
}

// ---------------------------------------------------------------------------
// Kernel 3: out = CTX @ Wo^T + bo via bf16x3 MFMA.
// ---------------------------------------------------------------------------
__global__ __launch_bounds__(256) void out_mfma_kernel(
    const ushort_t* __restrict__ CTXh, const ushort_t* __restrict__ CTXl,
    const float* __restrict__ Wo, const float* __restrict__ bo,
    float* __restrict__ out)
{
    const int mt = blockIdx.x;   // 0..63
    const int nt = blockIdx.y;   // 0..11

    __shared__ __align__(16) ushort_t Ah[128 * 64];
    __shared__ __align__(16) ushort_t Al[128 * 64];
    __shared__ __align__(16) ushort_t Bh[64 * 64];
    __shared__ __align__(16) ushort_t Bl[64 * 64];

    const int tid  = threadIdx.x;
    const int lane = tid & 63;
    const int lr   = lane & 15, lg = lane >> 4;
    const int wid  = tid >> 6;
    const int wm   = wid >> 1, wn = wid & 1;
    const int m0   = mt * 128, n0 = nt * 64;

    f32x4 acc[4][2] = {};

    for (int k0 = 0; k0 < Dn; k0 += 64) {
        if (k0) __syncthreads();
        #pragma unroll
        for (int t = 0; t < 4; ++t) {
            int c = tid + t * 256;
            int r = c >> 3, sl = (c & 7) ^ (r & 7);
            size_t go = (size_t)(m0 + r) * Dn + k0 + sl * 8;
            GLL16(CTXh + go, &Ah[c * 8]);
            GLL16(CTXl + go, &Al[c * 8]);
        }
        // B: load Wo f32, split to hi/lo bf16, swizzled LDS write
        #pragma unroll
        for (int t = 0; t < 4; ++t) {
            int idx = tid + t * 256;          // 0..1023 float4-quads
            int n = idx >> 4, f4 = idx & 15;
            float4 f = *(const float4*)&Wo[(size_t)(n0 + n) * Dn + k0 + f4 * 4];
            ushort_t h0 = bf_hi(f.x), h1 = bf_hi(f.y);
            ushort_t h2 = bf_hi(f.z), h3 = bf_hi(f.w);
            unsigned int hi0 = (unsigned)h0 | ((unsigned)h1 << 16);
            unsigned int hi1 = (unsigned)h2 | ((unsigned)h3 << 16);
            unsigned int lo0 = (unsigned)bf_hi(f.x - bf_f(h0)) |
                               ((unsigned)bf_hi(f.y - bf_f(h1)) << 16);
            unsigned int lo1 = (unsigned)bf_hi(f.z - bf_f(h2)) |
                               ((unsigned)bf_hi(f.w - bf_f(h3)) << 16);
            int di = (n * 64 + f4 * 4) ^ ((n & 7) << 3);
            *(uint2*)&Bh[di] = make_uint2(hi0, hi1);
            *(uint2*)&Bl[di] = make_uint2(lo0, lo1);
        }
        __syncthreads();

        #pragma unroll
        for (int ks = 0; ks < 2; ++ks) {
            const int kb = ks * 32 + lg * 8;
            bf16x8 a_h[4], a_l[4], b_h[2], b_l[2];
            #pragma unroll
            for (int i = 0; i < 4; ++i) {
                int row = wm * 64 + i * 16 + lr;
                int ai = (row * 64 + kb) ^ ((row & 7) << 3);
                a_h[i] = *(const bf16x8*)&Ah[ai];
                a_l[i] = *(const bf16x8*)&Al[ai];
            }
            #pragma unroll
            for (int j = 0; j < 2; ++j) {
                int col = wn * 32 + j * 16 + lr;
                int bi = (col * 64 + kb) ^ ((col & 7) << 3);
                b_h[j] = *(const bf16x8*)&Bh[bi];
                b_l[j] = *(const bf16x8*)&Bl[bi];
            }
            #pragma unroll
            for (int i = 0; i < 4; ++i)
                #pragma unroll
                for (int j = 0; j < 2; ++j) {
                    acc[i][j] = MFMA(a_h[i], b_h[j], acc[i][j]);
                    acc[i][j] = MFMA(a_l[i], b_h[j], acc[i][j]);
                    acc[i][j] = MFMA(a_h[i], b_l[j], acc[i][j]);
                }
        }
    }

    #pragma unroll
    for (int j = 0; j < 2; ++j) {
        int col = n0 + wn * 32 + j * 16 + lr;
        float bb = bo[col];
        #pragma unroll
        for (int i = 0; i < 4; ++i)
            #pragma unroll
            for (int r = 0; r < 4; ++r) {
                int m = m0 + wm * 64 + i * 16 + lg * 4 + r;
                out[(size_t)m * Dn + col] = acc[i][j][r] + bb;
            }
    }
}

// ---------------------------------------------------------------------------
extern "C" void kernel_launch(void* const* d_in, const int* in_sizes, int n_in,
                              void* d_out, int out_size, void* d_ws, size_t ws_size,
                              hipStream_t stream)
{
    const float* x  = (const float*)d_in[0];
    const float* Wq = (const float*)d_in[1];
    const float* bq = (const float*)d_in[2];
    const float* Wk = (const float*)d_in[3];
    const float* bk = (const float*)d_in[4];
    const float* Wv = (const float*)d_in[5];
    const float* bv = (const float*)d_in[6];
    const float* Wo = (const float*)d_in[7];
    const float* bo = (const float*)d_in[8];

    float* out = (float*)d_out;
    const size_t QSZ = (size_t)Bn * Hn * Sn * En;      // 6,291,456 elements
    float* probs = out + (size_t)Bn * Sn * Dn;         // probs region of d_out

    // ws layout (ushort arrays, total = old 4*QSZ float footprint):
    ushort_t* u   = (ushort_t*)d_ws;
    ushort_t* Qh  = u;
    ushort_t* Ql  = Qh + QSZ;
    ushort_t* Kh  = Ql + QSZ;
    ushort_t* Kl  = Kh + QSZ;
    ushort_t* Vth = Kl + QSZ;
    ushort_t* Vtl = Vth + QSZ;
    ushort_t* xh  = Vtl + QSZ;          // dead after qkv ...
    ushort_t* xl  = xh + (size_t)Mn * Dn;
    ushort_t* CTXh = xh;                // ... reused as CTX hi/lo
    ushort_t* CTXl = xl;

    // QKV weight splits live at the head of the probs region (dead before
    // attn_kernel overwrites all of probs).
    ushort_t* wth = (ushort_t*)probs;
    ushort_t* wtl = wth + (size_t)3 * Hn * En * Dn;

    split_x_kernel<<<dim3(Mn * Dn / 4 / 256), 256, 0, stream>>>(
        (const float4*)x, xh, xl);

    split_w_kernel<<<dim3(Dn / 64, Hn, 3), 256, 0, stream>>>(
        Wq, Wk, Wv, wth, wtl);

    qkv_mfma_kernel<<<dim3(Mn / 128, Hn, 3), 256, 0, stream>>>(
        xh, xl, wth, wtl, bq, bk, bv, Qh, Ql, Kh, Kl, Vth, Vtl);

    attn_kernel<<<dim3(Sn / 128 * Bn * Hn), 256, 0, stream>>>(
        Qh, Ql, Kh, Kl, Vth, Vtl, probs, CTXh, CTXl);

    out_mfma_kernel<<<dim3(Mn / 128, Dn / 64), 256, 0, stream>>>(
        CTXh, CTXl, Wo, bo, out);
}